// Round 6
// baseline (305.481 us; speedup 1.0000x reference)
//
#include <hip/hip_runtime.h>
#include <cmath>

// SSIM over (32,3,512,512) f32 pairs, 11x11 separable gaussian, valid conv,
// scalar mean output. Round 6: band geometry 32x54 outputs with a 64-row
// h-buffer so Phase A is EXACTLY 2 static tasks/thread (64 rows x 8 col-groups
// = 512 tasks), fully unrolled with all 16 float4 global loads batched before
// any conv math (latency hiding; R5 was 44% VALUBusy with nothing else busy).
// Conflict-free LDS maps carried over from R5 (write: row in low 3 task bits;
// read: row-shared 8-lane phases) -- R5 measured ~0 conflicts.

#define HH 512
#define WW 512
#define OH 502           // 512 - 11 + 1
#define OW 502
#define NC 96            // 32 * 3
#define TXS 32           // strip width (output cols)
#define TYB 54           // band height (output rows)
#define INR 64           // h-buffer rows = TYB + 10
#define HP4 33           // row stride in float4s (528 B -> 4-bank row rotation)
#define GX 16
#define GY 10            // ceil(502 / 54)
#define NSLOT 64         // f64 accumulator slots, 64 B apart

typedef float f4 __attribute__((ext_vector_type(4)));

struct GaussW { float g[11]; };

static __device__ __forceinline__ f4 sp(float s) { return (f4){s, s, s, s}; }

static __device__ __forceinline__ void load16(float* v, const float* p) {
    const float4* q = (const float4*)p;       // p is 16B-aligned (gc mult of 4)
    float4 a = q[0], b = q[1], c = q[2], d = q[3];
    v[0]=a.x;  v[1]=a.y;  v[2]=a.z;  v[3]=a.w;
    v[4]=b.x;  v[5]=b.y;  v[6]=b.z;  v[7]=b.w;
    v[8]=c.x;  v[9]=c.y;  v[10]=c.z; v[11]=c.w;
    v[12]=d.x; v[13]=d.y; v[14]=d.z; v[15]=d.w;
}

static __device__ __forceinline__ void load16c(float* v, const float* row, int gc) {
    #pragma unroll
    for (int i = 0; i < 16; ++i)              // clamped cols feed masked outputs
        v[i] = row[min(gc + i, WW - 1)];
}

// horizontal 11-tap conv of 4 maps (x, y, x^2+y^2, x*y) for 4 output cols,
// raw domain (sum(g)=1 lets the [-1,1]->[0,1] normalization fold into epilogue)
static __device__ __forceinline__ void conv_store(f4 (*hS)[HP4], const GaussW& gw,
        int r, int cg, const float* xv, const float* yv) {
    f4 a0 = sp(0.f), a1 = sp(0.f), a2 = sp(0.f), a3 = sp(0.f);
    #pragma unroll
    for (int k = 0; k < 14; ++k) {
        float x = xv[k], y = yv[k];
        f4 P;
        P.x = x; P.y = y;
        P.z = fmaf(x, x, y * y);
        P.w = x * y;
        #pragma unroll
        for (int j = 0; j < 4; ++j) {
            int u = k - j;
            if (u >= 0 && u < 11) {           // statically resolved
                f4 G = sp(gw.g[u]);
                if (j == 0) a0 = __builtin_elementwise_fma(G, P, a0);
                if (j == 1) a1 = __builtin_elementwise_fma(G, P, a1);
                if (j == 2) a2 = __builtin_elementwise_fma(G, P, a2);
                if (j == 3) a3 = __builtin_elementwise_fma(G, P, a3);
            }
        }
    }
    hS[r][4 * cg + 0] = a0;                   // conflict-free b128 writes:
    hS[r][4 * cg + 1] = a1;                   // 8-lane phase = 8 distinct rows,
    hS[r][4 * cg + 2] = a2;                   // start banks 4(r+c) disjoint
    hS[r][4 * cg + 3] = a3;
}

__global__ __launch_bounds__(256, 4) void ssim_kernel(
        const float* __restrict__ X, const float* __restrict__ Y,
        double* __restrict__ acc, GaussW gw) {
    // hS[r][c] = f4(conv_h(x), conv_h(y), conv_h(x^2+y^2), conv_h(x*y)).
    // 64*33*16 = 33792 B -> 4 blocks/CU.
    __shared__ f4 hS[INR][HP4];
    __shared__ float wsum[4];

    const int tid = threadIdx.x;
    const int R0 = blockIdx.y * TYB;
    const int C0 = blockIdx.x * TXS;
    const float* Xp = X + (size_t)blockIdx.z * (HH * WW);
    const float* Yp = Y + (size_t)blockIdx.z * (HH * WW);
    const bool edge = (blockIdx.x == GX - 1);   // reads would pass col 511

    // ---- Phase A: 2 static tasks/thread; task = (row | col-group).
    // Row in LOW 3 bits -> an 8-lane service phase sees 8 different rows.
    const int t0 = tid, t1 = tid + 256;
    const int r0 = (t0 & 7) | ((t0 >> 6) << 3), cg0 = (t0 >> 3) & 7;
    const int r1 = (t1 & 7) | ((t1 >> 6) << 3), cg1 = (t1 >> 3) & 7;
    const int gr0 = min(R0 + r0, HH - 1);       // clamp feeds masked rows only
    const int gr1 = min(R0 + r1, HH - 1);
    const int gc0 = C0 + 4 * cg0, gc1 = C0 + 4 * cg1;

    float xv0[16], yv0[16], xv1[16], yv1[16];
    if (!edge) {                                // all 16 loads issued up front
        load16(xv0, Xp + gr0 * WW + gc0);
        load16(yv0, Yp + gr0 * WW + gc0);
        load16(xv1, Xp + gr1 * WW + gc1);
        load16(yv1, Yp + gr1 * WW + gc1);
    } else {
        load16c(xv0, Xp + gr0 * WW, gc0);
        load16c(yv0, Yp + gr0 * WW, gc0);
        load16c(xv1, Xp + gr1 * WW, gc1);
        load16c(yv1, Yp + gr1 * WW, gc1);
    }
    conv_store(hS, gw, r0, cg0, xv0, yv0);
    conv_store(hS, gw, r1, cg1, xv1, yv1);
    __syncthreads();

    // ---- Phase B: vertical 11-tap conv + SSIM. 8 groups x 32 cols,
    // 7 output rows/thread, 17 row-reads (clamped; clamps feed masked rows).
    const int c  = tid & 31;
    const int rb = (tid >> 5) * 7;              // 0,7,...,49
    f4 A[7];
    #pragma unroll
    for (int j = 0; j < 7; ++j) A[j] = sp(0.f);
    #pragma unroll
    for (int k = 0; k < 17; ++k) {
        f4 v = hS[min(rb + k, INR - 1)][c];     // one ds_read_b128 per tap-row
        #pragma unroll
        for (int j = 0; j < 7; ++j) {
            int u = k - j;
            if (u >= 0 && u < 11) {
                f4 G = sp(gw.g[u]);
                A[j] = __builtin_elementwise_fma(G, v, A[j]);
            }
        }
    }

    // Epilogue: raw-domain fixup. With u=(x+1)/2: 2*mu = cx+1,
    // sigma1^2+sigma2^2 = (cs - cx^2 - cy^2)/4, sigma12 = (cp - cx*cy)/4.
    const float C1 = 1.0e-4f;
    const float C2 = 9.0e-4f;
    float nn[7], dd[7];
    #pragma unroll
    for (int j = 0; j < 7; ++j) {
        f4 v = A[j];
        float t1f = v.x + 1.f, t2f = v.y + 1.f;  // 2*mu1, 2*mu2
        float num1 = fmaf(t1f * t2f, 0.5f, C1);  // 2*mu1*mu2 + C1
        float den1 = fmaf(fmaf(t2f, t2f, t1f * t1f), 0.25f, C1);
        float num2 = fmaf(v.w - v.x * v.y, 0.5f, C2);   // 2*sigma12 + C2
        float den2 = fmaf(v.z - fmaf(v.x, v.x, v.y * v.y), 0.25f, C2);
        int row = rb + j;
        bool valid = (row < TYB) & (R0 + row < OH) & (C0 + c < OW);
        nn[j] = valid ? num1 * num2 : 0.f;
        dd[j] = valid ? den1 * den2 : 1.f;
    }
    // 2 divides for 7 outputs via common denominators (4+3 split).
    // dd >= C1*C2 ~ 9e-8; worst 4-product ~ 6.6e-29 stays normal in f32.
    float d01 = dd[0] * dd[1], d23 = dd[2] * dd[3];
    float s01 = fmaf(nn[0], dd[1], nn[1] * dd[0]);
    float s23 = fmaf(nn[2], dd[3], nn[3] * dd[2]);
    float tA  = fmaf(s01, d23, s23 * d01) / (d01 * d23);
    float d45 = dd[4] * dd[5];
    float s45 = fmaf(nn[4], dd[5], nn[5] * dd[4]);
    float tB  = fmaf(s45, dd[6], nn[6] * d45) / (d45 * dd[6]);
    float tsum = tA + tB;

    // f32 butterfly reduce (pairwise tree: error ~1e-6 absolute per block,
    // negligible vs 1.1e-4 threshold on the global mean), f64 only at atomic.
    #pragma unroll
    for (int off = 32; off > 0; off >>= 1)
        tsum += __shfl_down(tsum, off, 64);
    if ((tid & 63) == 0) wsum[tid >> 6] = tsum;
    __syncthreads();
    if (tid == 0) {
        double t = (double)wsum[0] + (double)wsum[1]
                 + (double)wsum[2] + (double)wsum[3];
        int slot = (blockIdx.x + blockIdx.y * GX + blockIdx.z * GX * GY) & (NSLOT - 1);
        atomicAdd(&acc[slot * 8], t);
    }
}

__global__ void ssim_finalize(const double* __restrict__ acc,
                              float* __restrict__ out) {
    int lane = threadIdx.x;                      // 64 threads, one slot each
    double t = acc[lane * 8];
    #pragma unroll
    for (int off = 32; off > 0; off >>= 1)
        t += __shfl_down(t, off, 64);
    if (lane == 0)
        out[0] = (float)(t * (1.0 / (double)((long long)NC * OH * OW)));
}

extern "C" void kernel_launch(void* const* d_in, const int* in_sizes, int n_in,
                              void* d_out, int out_size, void* d_ws, size_t ws_size,
                              hipStream_t stream) {
    const float* X = (const float*)d_in[0];
    const float* Y = (const float*)d_in[1];
    float* out = (float*)d_out;
    double* acc = (double*)d_ws;                 // 64 slots x 64 B = 4 KB

    // d_ws is re-poisoned to 0xAA before every timed launch: zero the slots.
    hipMemsetAsync(d_ws, 0, NSLOT * 64, stream);

    // Gaussian weights (win=11, sigma=1.5), computed in f64, passed by value.
    GaussW gw;
    {
        double g[11], s = 0.0;
        for (int i = 0; i < 11; ++i) {
            double d = (double)(i - 5);
            g[i] = exp(-d * d / (2.0 * 1.5 * 1.5));
            s += g[i];
        }
        for (int i = 0; i < 11; ++i) gw.g[i] = (float)(g[i] / s);
    }

    dim3 grid(GX, GY, NC);
    ssim_kernel<<<grid, dim3(256), 0, stream>>>(X, Y, acc, gw);
    ssim_finalize<<<1, dim3(64), 0, stream>>>(acc, out);
}